// Round 5
// baseline (191.860 us; speedup 1.0000x reference)
//
#include <hip/hip_runtime.h>
#include <hip/hip_fp16.h>

// ContinuousFilterConv on MI355X (gfx950), round 5.
// filtered[e,i] = sum_{u,j} h[e,u] * tm[e,j] * W2ext[u, i*128+j]
// GEMM C[8192x128] = A[8192x16512] @ B[16512x128], f16 MFMA, A generated on
// the fly (outer product h x tm). Round 5: K split over 16 u-chunks (was 8)
// -> grid 1024, 4 blocks/CU, 4 waves/SIMD, to hide B-load L2 latency under
// partner-wave MFMAs. Main loop stays barrier-free, LDS-free, reg-dbuf B.

typedef _Float16 f16;
typedef __attribute__((ext_vector_type(8))) f16 f16x8;
typedef __attribute__((ext_vector_type(4))) float f32x4;
typedef __attribute__((ext_vector_type(4))) unsigned int u32x4;

#define NEDGE 8192
#define NNODE 20000
#define NG    50
#define KSTEPS 516                       // 129 u-rows * 128 j / 32
#define W2C_BYTES (KSTEPS * 8192)        // [step][nt8][lane64][8] f16
#define HT_BYTES (64 * 132 * 128 * 2)    // [eb][u(132, 128=ones)][el(128)] f16
#define TM_BYTES (NEDGE * 128 * 2)       // [e][j^swz] f16 (mask folded, pre-swizzled)

// k2 LDS map (bytes) — prologue staging only
#define LDS_H   0                        // 12 rows x 256 B = 3072
#define LDS_TM  3072                     // 128 x 256 B (swizzled) = 32768
#define LDS_TOT 35840

static __device__ __forceinline__ float fsilu(float x) { return x / (1.0f + __expf(-x)); }

static __device__ __forceinline__ void gll16(const void* g, void* l) {
  __builtin_amdgcn_global_load_lds(
      (const __attribute__((address_space(1))) unsigned int*)g,
      (__attribute__((address_space(3))) unsigned int*)l, 16, 0, 0);
}

// ---------------- k0: W2 (+b2) -> f16, MFMA-B fragment-linear per K-step ----
__global__ __launch_bounds__(256) void k0_w2c(const float* __restrict__ W2,
                                              const float* __restrict__ b2,
                                              f16* __restrict__ w2c) {
  int gidx = blockIdx.x * 256 + threadIdx.x;   // 16B-group id, 516*512 total
  int lane = gidx & 63;
  int nt   = (gidx >> 6) & 7;
  int step = gidx >> 9;
  int k0i = step * 32 + (lane >> 4) * 8;       // first k of this group
  int i   = nt * 16 + (lane & 15);
  int u   = k0i >> 7, j0 = k0i & 127;
  const float* src = (u < 128) ? (W2 + (size_t)u * 16384 + i * 128 + j0)
                               : (b2 + i * 128 + j0);
  union { f16 s[8]; u32x4 v; } pk;
#pragma unroll
  for (int r = 0; r < 8; ++r) pk.s[r] = (f16)src[r];
  *((u32x4*)w2c + gidx) = pk.v;
}

// ---------------- k1: per-edge h and tm = mask * (src@Wt) -------------------
__global__ __launch_bounds__(256) void k1_edge(const float* __restrict__ NF,
                                               const int*   __restrict__ EI,
                                               const float* __restrict__ DI,
                                               const float* __restrict__ W1,
                                               const float* __restrict__ B1,
                                               const float* __restrict__ WT,
                                               f16* __restrict__ ht2,
                                               f16* __restrict__ tmo) {
  __shared__ float df[16][NG];
  __shared__ float s_mask[16];
  __shared__ float s_src[16][128];
  __shared__ float t_tile[16][132];
  __shared__ float h_tile[16][132];
  int et = blockIdx.x, e0 = et * 16, tid = threadIdx.x;

  for (int idx = tid; idx < 16 * NG; idx += 256) {
    int e = idx / NG, g = idx - e * NG;
    float d = DI[e0 + e];
    float x = d - (float)g * (30.0f / 49.0f);
    df[e][g] = __expf(-10.0f * x * x);
  }
  if (tid < 16) s_mask[tid] = (DI[e0 + tid] <= 8.0f) ? 1.0f : 0.0f;
  for (int idx = tid; idx < 16 * 128; idx += 256) {
    int e = idx >> 7, u = idx & 127;
    s_src[e][u] = NF[(size_t)EI[e0 + e] * 128 + u];
  }
  __syncthreads();

  int j = tid & 127, es = tid >> 7;
  for (int e = es * 8; e < es * 8 + 8; ++e) {
    float acc = B1[j];
    for (int g = 0; g < NG; ++g) acc += df[e][g] * W1[g * 128 + j];
    h_tile[e][j] = fsilu(acc);
  }
  {
    float acc[8] = {0.f,0.f,0.f,0.f,0.f,0.f,0.f,0.f};
    for (int u = 0; u < 128; ++u) {
      float wv = WT[u * 128 + j];
#pragma unroll
      for (int e8 = 0; e8 < 8; ++e8) acc[e8] += s_src[es * 8 + e8][u] * wv;
    }
#pragma unroll
    for (int e8 = 0; e8 < 8; ++e8) t_tile[es * 8 + e8][j] = acc[e8];
  }
  __syncthreads();

  int eb = et >> 3, el0 = (et & 7) * 16;
  // ht2[eb][u][el]: tid -> (u = tid>>1, half = tid&1)
  {
    int u = tid >> 1, hf = tid & 1;
    union { f16 s[8]; u32x4 v; } pk;
#pragma unroll
    for (int k = 0; k < 8; ++k) pk.s[k] = (f16)h_tile[hf * 8 + k][u];
    *(u32x4*)(ht2 + ((size_t)eb * 132 + u) * 128 + el0 + hf * 8) = pk.v;
  }
  if (tid < 16) ht2[((size_t)eb * 132 + 128) * 128 + el0 + tid] = (f16)1.0f; // ones (b2)
  // tm[e][j], mask folded, PRE-SWIZZLED column: tid -> (e = tid>>4, chunk = tid&15)
  {
    int e = tid >> 4, cc = tid & 15;
    float m = s_mask[e];
    union { f16 s[8]; u32x4 v; } pk;
#pragma unroll
    for (int k = 0; k < 8; ++k) pk.s[k] = (f16)(m * t_tile[e][cc * 8 + k]);
    int col = (cc * 16) ^ ((e & 7) << 4);
    *(u32x4*)((char*)tmo + (size_t)(e0 + e) * 256 + col) = pk.v;
  }
}

// ---------------- k2: fused outer-product GEMM + scatter-add ----------------
// grid 1024: chunk c = bid&15 (8 u, c==15: 9 incl. b2 row), eb = bid>>4.
// Block: 4 waves 2x2 over 128e x 128i; wave = 64e x 64i; acc[4][4] f32x4.
// Main loop: no barriers, no LDS. tm frags in VGPRs; B global->reg dbuf.
__global__ __launch_bounds__(256, 4) void k2_gemm(const f16* __restrict__ w2c,
                                                  const f16* __restrict__ ht2,
                                                  const f16* __restrict__ tm,
                                                  const int* __restrict__ EI,
                                                  float* __restrict__ msg) {
  __shared__ u32x4 smem_v[LDS_TOT / 16];
  char* smem = (char*)smem_v;

  const int bid = blockIdx.x;
  const int c   = bid & 15;
  const int eb  = bid >> 4;
  const int e0  = eb * 128;
  const int nu  = (c == 15) ? 9 : 8;
  const int tid = threadIdx.x, w = tid >> 6, lane = tid & 63;
  const int l15 = lane & 15, g4 = lane >> 4;
  const int wm = w >> 1, wn = w & 1;

  // ---- prologue staging (tm swizzled + h), one-time ----
  {
    const char* tsrc = (const char*)tm + (size_t)e0 * 256 + w * 8192;
#pragma unroll
    for (int q = 0; q < 8; ++q)
      gll16(tsrc + q * 1024 + lane * 16,
            smem + LDS_TM + w * 8192 + q * 1024 + lane * 16);
  }
  if (w == 0) {   // 12 h rows (u0 .. u0+11); only u0..u0+nu-1 ever read
    const char* hsrc = (const char*)ht2 + ((size_t)eb * 132 + c * 8) * 256;
#pragma unroll
    for (int q = 0; q < 3; ++q)
      gll16(hsrc + q * 1024 + lane * 16, smem + LDS_H + q * 1024 + lane * 16);
  }
  __syncthreads();

  // ---- tm A-frags: u-invariant -> load ALL into registers once ----
  f16x8 Tall[4][4];
  {
    const int tmrow = LDS_TM + (wm * 64 + l15) * 256;
    const int colsw = (l15 & 7) << 4;
#pragma unroll
    for (int rt = 0; rt < 4; ++rt)
#pragma unroll
      for (int jc = 0; jc < 4; ++jc)
        Tall[rt][jc] = *(const f16x8*)(smem + tmrow + rt * 4096 +
                                       ((jc * 64 + g4 * 16) ^ colsw));
  }
  const __half* hbase = (const __half*)(smem + LDS_H) + wm * 64 + l15;

  __half2 hc[4], hn[4];
#pragma unroll
  for (int rt = 0; rt < 4; ++rt) hc[rt] = __half2half2(hbase[rt * 16]);

  // ---- B stream: global->reg, double-buffered ----
  const char* bp = (const char*)w2c + (size_t)(c * 32) * 8192 + wn * 4096 + lane * 16;
  f16x8 Bc[4], Bn[4];
#pragma unroll
  for (int nt = 0; nt < 4; ++nt) Bn[nt] = *(const f16x8*)(bp + nt * 1024);
  bp += 8192;

  f32x4 acc[4][4];
#pragma unroll
  for (int rt = 0; rt < 4; ++rt)
#pragma unroll
    for (int nt = 0; nt < 4; ++nt) acc[rt][nt] = (f32x4){0.f, 0.f, 0.f, 0.f};

  for (int u = 0; u < nu; ++u) {
#pragma unroll
    for (int jc = 0; jc < 4; ++jc) {
#pragma unroll
      for (int nt = 0; nt < 4; ++nt) Bc[nt] = Bn[nt];
      // prefetch next phase's B (tail prefetch runs past chunk: in-bounds, unused)
#pragma unroll
      for (int nt = 0; nt < 4; ++nt) Bn[nt] = *(const f16x8*)(bp + nt * 1024);
      bp += 8192;
      if (jc == 1) {   // prefetch next u's h (broadcast LDS reads, rows < 12 staged)
#pragma unroll
        for (int rt = 0; rt < 4; ++rt)
          hn[rt] = __half2half2(hbase[(u + 1) * 128 + rt * 16]);
      }
      // A-gen from register-resident tm frags
      union uf { f16x8 v; __half2 h[4]; };
      uf a[4];
#pragma unroll
      for (int rt = 0; rt < 4; ++rt) {
        uf t; t.v = Tall[rt][jc];
#pragma unroll
        for (int q = 0; q < 4; ++q) a[rt].h[q] = __hmul2(t.h[q], hc[rt]);
      }
      __builtin_amdgcn_s_setprio(1);
#pragma unroll
      for (int nt = 0; nt < 4; ++nt)
#pragma unroll
        for (int rt = 0; rt < 4; ++rt)
          acc[rt][nt] = __builtin_amdgcn_mfma_f32_16x16x32_f16(a[rt].v, Bc[nt], acc[rt][nt], 0, 0, 0);
      __builtin_amdgcn_s_setprio(0);
    }
#pragma unroll
    for (int rt = 0; rt < 4; ++rt) hc[rt] = hn[rt];
  }

  // epilogue: scatter-add partials (C map: row=(g4*4+r), col=l15 per 16x16 frag)
  const int* dst = EI + NEDGE;
#pragma unroll
  for (int rt = 0; rt < 4; ++rt) {
#pragma unroll
    for (int r = 0; r < 4; ++r) {
      int e = e0 + wm * 64 + rt * 16 + g4 * 4 + r;
      float* row = msg + (size_t)dst[e] * 128 + wn * 64 + l15;
#pragma unroll
      for (int nt = 0; nt < 4; ++nt)
        atomicAdd(row + nt * 16, acc[rt][nt][r]);
    }
  }
}

// ---------------- k3: out = silu(messages) ----------------------------------
__global__ __launch_bounds__(256) void k3_silu(float* __restrict__ out, int n4) {
  int idx = blockIdx.x * 256 + threadIdx.x;
  int stride = gridDim.x * 256;
  f32x4* p = (f32x4*)out;
  for (; idx < n4; idx += stride) {
    f32x4 v = p[idx];
#pragma unroll
    for (int cc = 0; cc < 4; ++cc) v[cc] = fsilu(v[cc]);
    p[idx] = v;
  }
}

extern "C" void kernel_launch(void* const* d_in, const int* in_sizes, int n_in,
                              void* d_out, int out_size, void* d_ws, size_t ws_size,
                              hipStream_t stream) {
  const float* NF = (const float*)d_in[0];
  const int*   EI = (const int*)  d_in[1];
  const float* DI = (const float*)d_in[2];
  const float* W1 = (const float*)d_in[3];
  const float* B1 = (const float*)d_in[4];
  const float* W2 = (const float*)d_in[5];
  const float* B2 = (const float*)d_in[6];
  const float* WT = (const float*)d_in[7];
  float* out = (float*)d_out;

  f16* w2c = (f16*)d_ws;
  f16* ht2 = (f16*)((char*)d_ws + W2C_BYTES);
  f16* tmo = (f16*)((char*)d_ws + W2C_BYTES + HT_BYTES);
  size_t needed = (size_t)W2C_BYTES + HT_BYTES + TM_BYTES;
  if (ws_size < needed) return;  // insufficient scratch: fail loudly

  hipMemsetAsync(d_out, 0, (size_t)out_size * sizeof(float), stream);
  k0_w2c <<<dim3(1032), dim3(256), 0, stream>>>(W2, B2, w2c);
  k1_edge<<<dim3(512),  dim3(256), 0, stream>>>(NF, EI, DI, W1, B1, WT, ht2, tmo);
  k2_gemm<<<dim3(1024), dim3(256), 0, stream>>>(w2c, ht2, tmo, EI, out);
  k3_silu<<<dim3(1024), dim3(256), 0, stream>>>(out, out_size / 4);
}

// Round 6
// 117.839 us; speedup vs baseline: 1.6282x; 1.6282x over previous
//
#include <hip/hip_runtime.h>
#include <hip/hip_fp16.h>

// ContinuousFilterConv on MI355X (gfx950), round 6.
// filtered[e,i] = sum_{u,j} h[e,u] * tm[e,j] * W2ext[u, i*128+j]
// GEMM C[8192x128] = A[8192x16512] @ B[16512x128], f16 MFMA, A generated on
// the fly (outer product h x tm). K split over 16 u-chunks, grid 1024
// (4 blocks/CU). Round 6: revert launch_bounds to (256,2) — round 5's (256,4)
// forced VGPR 100->64 and spilled to scratch (FETCH 12->300 MB, MfmaUtil 8%).
// Main loop stays barrier-free, LDS-free, reg-dbuf B.

typedef _Float16 f16;
typedef __attribute__((ext_vector_type(8))) f16 f16x8;
typedef __attribute__((ext_vector_type(4))) float f32x4;
typedef __attribute__((ext_vector_type(4))) unsigned int u32x4;

#define NEDGE 8192
#define NNODE 20000
#define NG    50
#define KSTEPS 516                       // 129 u-rows * 128 j / 32
#define W2C_BYTES (KSTEPS * 8192)        // [step][nt8][lane64][8] f16
#define HT_BYTES (64 * 132 * 128 * 2)    // [eb][u(132, 128=ones)][el(128)] f16
#define TM_BYTES (NEDGE * 128 * 2)       // [e][j^swz] f16 (mask folded, pre-swizzled)

// k2 LDS map (bytes) — prologue staging only
#define LDS_H   0                        // 12 rows x 256 B = 3072
#define LDS_TM  3072                     // 128 x 256 B (swizzled) = 32768
#define LDS_TOT 35840

static __device__ __forceinline__ float fsilu(float x) { return x / (1.0f + __expf(-x)); }

static __device__ __forceinline__ void gll16(const void* g, void* l) {
  __builtin_amdgcn_global_load_lds(
      (const __attribute__((address_space(1))) unsigned int*)g,
      (__attribute__((address_space(3))) unsigned int*)l, 16, 0, 0);
}

// ---------------- k0: W2 (+b2) -> f16, MFMA-B fragment-linear per K-step ----
__global__ __launch_bounds__(256) void k0_w2c(const float* __restrict__ W2,
                                              const float* __restrict__ b2,
                                              f16* __restrict__ w2c) {
  int gidx = blockIdx.x * 256 + threadIdx.x;   // 16B-group id, 516*512 total
  int lane = gidx & 63;
  int nt   = (gidx >> 6) & 7;
  int step = gidx >> 9;
  int k0i = step * 32 + (lane >> 4) * 8;       // first k of this group
  int i   = nt * 16 + (lane & 15);
  int u   = k0i >> 7, j0 = k0i & 127;
  const float* src = (u < 128) ? (W2 + (size_t)u * 16384 + i * 128 + j0)
                               : (b2 + i * 128 + j0);
  union { f16 s[8]; u32x4 v; } pk;
#pragma unroll
  for (int r = 0; r < 8; ++r) pk.s[r] = (f16)src[r];
  *((u32x4*)w2c + gidx) = pk.v;
}

// ---------------- k1: per-edge h and tm = mask * (src@Wt) -------------------
__global__ __launch_bounds__(256) void k1_edge(const float* __restrict__ NF,
                                               const int*   __restrict__ EI,
                                               const float* __restrict__ DI,
                                               const float* __restrict__ W1,
                                               const float* __restrict__ B1,
                                               const float* __restrict__ WT,
                                               f16* __restrict__ ht2,
                                               f16* __restrict__ tmo) {
  __shared__ float df[16][NG];
  __shared__ float s_mask[16];
  __shared__ float s_src[16][128];
  __shared__ float t_tile[16][132];
  __shared__ float h_tile[16][132];
  int et = blockIdx.x, e0 = et * 16, tid = threadIdx.x;

  for (int idx = tid; idx < 16 * NG; idx += 256) {
    int e = idx / NG, g = idx - e * NG;
    float d = DI[e0 + e];
    float x = d - (float)g * (30.0f / 49.0f);
    df[e][g] = __expf(-10.0f * x * x);
  }
  if (tid < 16) s_mask[tid] = (DI[e0 + tid] <= 8.0f) ? 1.0f : 0.0f;
  for (int idx = tid; idx < 16 * 128; idx += 256) {
    int e = idx >> 7, u = idx & 127;
    s_src[e][u] = NF[(size_t)EI[e0 + e] * 128 + u];
  }
  __syncthreads();

  int j = tid & 127, es = tid >> 7;
  for (int e = es * 8; e < es * 8 + 8; ++e) {
    float acc = B1[j];
    for (int g = 0; g < NG; ++g) acc += df[e][g] * W1[g * 128 + j];
    h_tile[e][j] = fsilu(acc);
  }
  {
    float acc[8] = {0.f,0.f,0.f,0.f,0.f,0.f,0.f,0.f};
    for (int u = 0; u < 128; ++u) {
      float wv = WT[u * 128 + j];
#pragma unroll
      for (int e8 = 0; e8 < 8; ++e8) acc[e8] += s_src[es * 8 + e8][u] * wv;
    }
#pragma unroll
    for (int e8 = 0; e8 < 8; ++e8) t_tile[es * 8 + e8][j] = acc[e8];
  }
  __syncthreads();

  int eb = et >> 3, el0 = (et & 7) * 16;
  // ht2[eb][u][el]: tid -> (u = tid>>1, half = tid&1)
  {
    int u = tid >> 1, hf = tid & 1;
    union { f16 s[8]; u32x4 v; } pk;
#pragma unroll
    for (int k = 0; k < 8; ++k) pk.s[k] = (f16)h_tile[hf * 8 + k][u];
    *(u32x4*)(ht2 + ((size_t)eb * 132 + u) * 128 + el0 + hf * 8) = pk.v;
  }
  if (tid < 16) ht2[((size_t)eb * 132 + 128) * 128 + el0 + tid] = (f16)1.0f; // ones (b2)
  // tm[e][j], mask folded, PRE-SWIZZLED column: tid -> (e = tid>>4, chunk = tid&15)
  {
    int e = tid >> 4, cc = tid & 15;
    float m = s_mask[e];
    union { f16 s[8]; u32x4 v; } pk;
#pragma unroll
    for (int k = 0; k < 8; ++k) pk.s[k] = (f16)(m * t_tile[e][cc * 8 + k]);
    int col = (cc * 16) ^ ((e & 7) << 4);
    *(u32x4*)((char*)tmo + (size_t)(e0 + e) * 256 + col) = pk.v;
  }
}

// ---------------- k2: fused outer-product GEMM + scatter-add ----------------
// grid 1024: chunk c = bid&15 (8 u, c==15: 9 incl. b2 row), eb = bid>>4.
// Block: 4 waves 2x2 over 128e x 128i; wave = 64e x 64i; acc[4][4] f32x4.
// Main loop: no barriers, no LDS. tm frags in VGPRs; B global->reg dbuf.
__global__ __launch_bounds__(256, 2) void k2_gemm(const f16* __restrict__ w2c,
                                                  const f16* __restrict__ ht2,
                                                  const f16* __restrict__ tm,
                                                  const int* __restrict__ EI,
                                                  float* __restrict__ msg) {
  __shared__ u32x4 smem_v[LDS_TOT / 16];
  char* smem = (char*)smem_v;

  const int bid = blockIdx.x;
  const int c   = bid & 15;
  const int eb  = bid >> 4;
  const int e0  = eb * 128;
  const int nu  = (c == 15) ? 9 : 8;
  const int tid = threadIdx.x, w = tid >> 6, lane = tid & 63;
  const int l15 = lane & 15, g4 = lane >> 4;
  const int wm = w >> 1, wn = w & 1;

  // ---- prologue staging (tm swizzled + h), one-time ----
  {
    const char* tsrc = (const char*)tm + (size_t)e0 * 256 + w * 8192;
#pragma unroll
    for (int q = 0; q < 8; ++q)
      gll16(tsrc + q * 1024 + lane * 16,
            smem + LDS_TM + w * 8192 + q * 1024 + lane * 16);
  }
  if (w == 0) {   // 12 h rows (u0 .. u0+11); only u0..u0+nu-1 ever read
    const char* hsrc = (const char*)ht2 + ((size_t)eb * 132 + c * 8) * 256;
#pragma unroll
    for (int q = 0; q < 3; ++q)
      gll16(hsrc + q * 1024 + lane * 16, smem + LDS_H + q * 1024 + lane * 16);
  }
  __syncthreads();

  // ---- tm A-frags: u-invariant -> load ALL into registers once ----
  f16x8 Tall[4][4];
  {
    const int tmrow = LDS_TM + (wm * 64 + l15) * 256;
    const int colsw = (l15 & 7) << 4;
#pragma unroll
    for (int rt = 0; rt < 4; ++rt)
#pragma unroll
      for (int jc = 0; jc < 4; ++jc)
        Tall[rt][jc] = *(const f16x8*)(smem + tmrow + rt * 4096 +
                                       ((jc * 64 + g4 * 16) ^ colsw));
  }
  const __half* hbase = (const __half*)(smem + LDS_H) + wm * 64 + l15;

  __half2 hc[4], hn[4];
#pragma unroll
  for (int rt = 0; rt < 4; ++rt) hc[rt] = __half2half2(hbase[rt * 16]);

  // ---- B stream: global->reg, double-buffered ----
  const char* bp = (const char*)w2c + (size_t)(c * 32) * 8192 + wn * 4096 + lane * 16;
  f16x8 Bc[4], Bn[4];
#pragma unroll
  for (int nt = 0; nt < 4; ++nt) Bn[nt] = *(const f16x8*)(bp + nt * 1024);
  bp += 8192;

  f32x4 acc[4][4];
#pragma unroll
  for (int rt = 0; rt < 4; ++rt)
#pragma unroll
    for (int nt = 0; nt < 4; ++nt) acc[rt][nt] = (f32x4){0.f, 0.f, 0.f, 0.f};

  for (int u = 0; u < nu; ++u) {
#pragma unroll
    for (int jc = 0; jc < 4; ++jc) {
#pragma unroll
      for (int nt = 0; nt < 4; ++nt) Bc[nt] = Bn[nt];
      // prefetch next phase's B (tail prefetch runs past chunk: in-bounds, unused)
#pragma unroll
      for (int nt = 0; nt < 4; ++nt) Bn[nt] = *(const f16x8*)(bp + nt * 1024);
      bp += 8192;
      if (jc == 1) {   // prefetch next u's h (broadcast LDS reads, rows < 12 staged)
#pragma unroll
        for (int rt = 0; rt < 4; ++rt)
          hn[rt] = __half2half2(hbase[(u + 1) * 128 + rt * 16]);
      }
      // A-gen from register-resident tm frags
      union uf { f16x8 v; __half2 h[4]; };
      uf a[4];
#pragma unroll
      for (int rt = 0; rt < 4; ++rt) {
        uf t; t.v = Tall[rt][jc];
#pragma unroll
        for (int q = 0; q < 4; ++q) a[rt].h[q] = __hmul2(t.h[q], hc[rt]);
      }
      __builtin_amdgcn_s_setprio(1);
#pragma unroll
      for (int nt = 0; nt < 4; ++nt)
#pragma unroll
        for (int rt = 0; rt < 4; ++rt)
          acc[rt][nt] = __builtin_amdgcn_mfma_f32_16x16x32_f16(a[rt].v, Bc[nt], acc[rt][nt], 0, 0, 0);
      __builtin_amdgcn_s_setprio(0);
    }
#pragma unroll
    for (int rt = 0; rt < 4; ++rt) hc[rt] = hn[rt];
  }

  // epilogue: scatter-add partials (C map: row=(g4*4+r), col=l15 per 16x16 frag)
  const int* dst = EI + NEDGE;
#pragma unroll
  for (int rt = 0; rt < 4; ++rt) {
#pragma unroll
    for (int r = 0; r < 4; ++r) {
      int e = e0 + wm * 64 + rt * 16 + g4 * 4 + r;
      float* row = msg + (size_t)dst[e] * 128 + wn * 64 + l15;
#pragma unroll
      for (int nt = 0; nt < 4; ++nt)
        atomicAdd(row + nt * 16, acc[rt][nt][r]);
    }
  }
}

// ---------------- k3: out = silu(messages) ----------------------------------
__global__ __launch_bounds__(256) void k3_silu(float* __restrict__ out, int n4) {
  int idx = blockIdx.x * 256 + threadIdx.x;
  int stride = gridDim.x * 256;
  f32x4* p = (f32x4*)out;
  for (; idx < n4; idx += stride) {
    f32x4 v = p[idx];
#pragma unroll
    for (int cc = 0; cc < 4; ++cc) v[cc] = fsilu(v[cc]);
    p[idx] = v;
  }
}

extern "C" void kernel_launch(void* const* d_in, const int* in_sizes, int n_in,
                              void* d_out, int out_size, void* d_ws, size_t ws_size,
                              hipStream_t stream) {
  const float* NF = (const float*)d_in[0];
  const int*   EI = (const int*)  d_in[1];
  const float* DI = (const float*)d_in[2];
  const float* W1 = (const float*)d_in[3];
  const float* B1 = (const float*)d_in[4];
  const float* W2 = (const float*)d_in[5];
  const float* B2 = (const float*)d_in[6];
  const float* WT = (const float*)d_in[7];
  float* out = (float*)d_out;

  f16* w2c = (f16*)d_ws;
  f16* ht2 = (f16*)((char*)d_ws + W2C_BYTES);
  f16* tmo = (f16*)((char*)d_ws + W2C_BYTES + HT_BYTES);
  size_t needed = (size_t)W2C_BYTES + HT_BYTES + TM_BYTES;
  if (ws_size < needed) return;  // insufficient scratch: fail loudly

  hipMemsetAsync(d_out, 0, (size_t)out_size * sizeof(float), stream);
  k0_w2c <<<dim3(1032), dim3(256), 0, stream>>>(W2, B2, w2c);
  k1_edge<<<dim3(512),  dim3(256), 0, stream>>>(NF, EI, DI, W1, B1, WT, ht2, tmo);
  k2_gemm<<<dim3(1024), dim3(256), 0, stream>>>(w2c, ht2, tmo, EI, out);
  k3_silu<<<dim3(1024), dim3(256), 0, stream>>>(out, out_size / 4);
}

// Round 7
// 91.988 us; speedup vs baseline: 2.0857x; 1.2810x over previous
//
#include <hip/hip_runtime.h>
#include <hip/hip_fp16.h>

// ContinuousFilterConv on MI355X (gfx950), round 7.
// filtered[e,i] = sum_{u,j} h[e,u] * tm[e,j] * W2ext[u, i*128+j]
// GEMM C[8192x128] = A[8192x16512] @ B[16512x128], f16 MFMA, A generated on
// the fly (outer product h x tm). K split over 8 u-chunks (c = XCD), grid 512.
// Round 7: 512-thread blocks, 8 waves of 32e x 64i (acc 32 + tm 32 + B ~32
// regs = ~118 total) under __launch_bounds__(512,4) -> 4 waves/SIMD resident
// (rounds 4-6 showed ~164 regs/wave capped residency at 2-3 waves/SIMD).
// Main loop stays barrier-free, LDS-free, reg-dbuf B. k0+k1+zero merged.

typedef _Float16 f16;
typedef __attribute__((ext_vector_type(8))) f16 f16x8;
typedef __attribute__((ext_vector_type(4))) float f32x4;
typedef __attribute__((ext_vector_type(4))) unsigned int u32x4;

#define NEDGE 8192
#define NNODE 20000
#define NG    50
#define KSTEPS 516                       // 129 u-rows * 128 j / 32
#define W2C_BYTES (KSTEPS * 8192)        // [step][nt8][lane64][8] f16
#define HT_BYTES (64 * 132 * 128 * 2)    // [eb][u(132, 128=ones)][el(128)] f16
#define TM_BYTES (NEDGE * 128 * 2)       // [e][j^swz] f16 (mask folded, pre-swizzled)

// k2 LDS map (bytes) — prologue staging only
#define LDS_H   0                        // 20 rows x 256 B = 5120
#define LDS_TM  5120                     // 128 x 256 B (swizzled) = 32768
#define LDS_TOT 37888

static __device__ __forceinline__ float fsilu(float x) { return x / (1.0f + __expf(-x)); }

static __device__ __forceinline__ void gll16(const void* g, void* l) {
  __builtin_amdgcn_global_load_lds(
      (const __attribute__((address_space(1))) unsigned int*)g,
      (__attribute__((address_space(3))) unsigned int*)l, 16, 0, 0);
}

// -------- k01: fused {W2->w2c frag convert | per-edge h,tm | zero out} ------
__global__ __launch_bounds__(256) void k01(const float* __restrict__ W2,
                                           const float* __restrict__ b2,
                                           const float* __restrict__ NF,
                                           const int*   __restrict__ EI,
                                           const float* __restrict__ DI,
                                           const float* __restrict__ W1,
                                           const float* __restrict__ B1,
                                           const float* __restrict__ WT,
                                           f16* __restrict__ w2c,
                                           f16* __restrict__ ht2,
                                           f16* __restrict__ tmo,
                                           float* __restrict__ out, int nz4) {
  __shared__ float df[16][NG];
  __shared__ float s_mask[16];
  __shared__ float s_src[16][128];
  __shared__ float t_tile[16][132];
  __shared__ float h_tile[16][132];
  const int bid = blockIdx.x, tid = threadIdx.x;

  if (bid < 1032) {
    // ---- k0 body: W2 (+b2) -> f16, MFMA-B fragment-linear per K-step ----
    int gidx = bid * 256 + tid;                  // 16B-group id, 516*512 total
    int lane = gidx & 63;
    int nt   = (gidx >> 6) & 7;
    int step = gidx >> 9;
    int k0i = step * 32 + (lane >> 4) * 8;       // first k of this group
    int i   = nt * 16 + (lane & 15);
    int u   = k0i >> 7, j0 = k0i & 127;
    const float* src = (u < 128) ? (W2 + (size_t)u * 16384 + i * 128 + j0)
                                 : (b2 + i * 128 + j0);
    union { f16 s[8]; u32x4 v; } pk;
#pragma unroll
    for (int r = 0; r < 8; ++r) pk.s[r] = (f16)src[r];
    *((u32x4*)w2c + gidx) = pk.v;
    return;
  }
  if (bid < 1544) {
    // ---- k1 body: per-edge h (unmasked) and tm = mask * (src@Wt) ----
    int et = bid - 1032, e0 = et * 16;
    for (int idx = tid; idx < 16 * NG; idx += 256) {
      int e = idx / NG, g = idx - e * NG;
      float d = DI[e0 + e];
      float x = d - (float)g * (30.0f / 49.0f);
      df[e][g] = __expf(-10.0f * x * x);
    }
    if (tid < 16) s_mask[tid] = (DI[e0 + tid] <= 8.0f) ? 1.0f : 0.0f;
    for (int idx = tid; idx < 16 * 128; idx += 256) {
      int e = idx >> 7, u = idx & 127;
      s_src[e][u] = NF[(size_t)EI[e0 + e] * 128 + u];
    }
    __syncthreads();

    int j = tid & 127, es = tid >> 7;
    for (int e = es * 8; e < es * 8 + 8; ++e) {
      float acc = B1[j];
      for (int g = 0; g < NG; ++g) acc += df[e][g] * W1[g * 128 + j];
      h_tile[e][j] = fsilu(acc);
    }
    {
      float acc[8] = {0.f,0.f,0.f,0.f,0.f,0.f,0.f,0.f};
      for (int u = 0; u < 128; ++u) {
        float wv = WT[u * 128 + j];
#pragma unroll
        for (int e8 = 0; e8 < 8; ++e8) acc[e8] += s_src[es * 8 + e8][u] * wv;
      }
#pragma unroll
      for (int e8 = 0; e8 < 8; ++e8) t_tile[es * 8 + e8][j] = acc[e8];
    }
    __syncthreads();

    int eb = et >> 3, el0 = (et & 7) * 16;
    // ht2[eb][u][el]: tid -> (u = tid>>1, half = tid&1)
    {
      int u = tid >> 1, hf = tid & 1;
      union { f16 s[8]; u32x4 v; } pk;
#pragma unroll
      for (int k = 0; k < 8; ++k) pk.s[k] = (f16)h_tile[hf * 8 + k][u];
      *(u32x4*)(ht2 + ((size_t)eb * 132 + u) * 128 + el0 + hf * 8) = pk.v;
    }
    if (tid < 16) ht2[((size_t)eb * 132 + 128) * 128 + el0 + tid] = (f16)1.0f; // ones (b2)
    // tm[e][j], mask folded, PRE-SWIZZLED column
    {
      int e = tid >> 4, cc = tid & 15;
      float m = s_mask[e];
      union { f16 s[8]; u32x4 v; } pk;
#pragma unroll
      for (int k = 0; k < 8; ++k) pk.s[k] = (f16)(m * t_tile[e][cc * 8 + k]);
      int col = (cc * 16) ^ ((e & 7) << 4);
      *(u32x4*)((char*)tmo + (size_t)(e0 + e) * 256 + col) = pk.v;
    }
    return;
  }
  // ---- zero d_out ----
  {
    int base = (bid - 1544) * 1024;
    f32x4 z = {0.f, 0.f, 0.f, 0.f};
#pragma unroll
    for (int k = 0; k < 4; ++k) {
      int i4 = base + k * 256 + tid;
      if (i4 < nz4) ((f32x4*)out)[i4] = z;
    }
  }
}

// ---------------- k2: fused outer-product GEMM + scatter-add ----------------
// grid 512: chunk c = bid&7 (16 u, c==7: 17 incl. b2 row), eb = bid>>3.
// Block: 512 threads, 8 waves over 128e x 128i; wave = 32e x 64i.
// wm = w>>1 (e-quarter), wn = w&1 (i-half). acc[2][4] f32x4 = 32 regs.
// Main loop: no barriers, no LDS. tm frags in VGPRs; B global->reg dbuf.
__global__ __launch_bounds__(512, 4) void k2_gemm(const f16* __restrict__ w2c,
                                                  const f16* __restrict__ ht2,
                                                  const f16* __restrict__ tm,
                                                  const int* __restrict__ EI,
                                                  float* __restrict__ msg) {
  __shared__ u32x4 smem_v[LDS_TOT / 16];
  char* smem = (char*)smem_v;

  const int bid = blockIdx.x;
  const int c   = bid & 7;
  const int eb  = bid >> 3;
  const int e0  = eb * 128;
  const int nu  = (c == 7) ? 17 : 16;
  const int tid = threadIdx.x, w = tid >> 6, lane = tid & 63;
  const int l15 = lane & 15, g4 = lane >> 4;
  const int wm = w >> 1, wn = w & 1;

  // ---- prologue staging (tm swizzled + h), one-time ----
  {
    const char* tsrc = (const char*)tm + (size_t)e0 * 256;
#pragma unroll
    for (int q = 0; q < 4; ++q) {
      int off = (q * 512 + tid) * 16;              // 2048 x 16B = 32 KB
      gll16(tsrc + off, smem + LDS_TM + off);
    }
  }
  if (tid < 320) {                                 // 20 h rows x 256 B
    const char* hsrc = (const char*)ht2 + ((size_t)eb * 132 + c * 16) * 256;
    gll16(hsrc + tid * 16, smem + LDS_H + tid * 16);
  }
  __syncthreads();

  // ---- tm A-frags (u-invariant): 8 frags = 32 regs ----
  f16x8 Tall[2][4];
  {
    const int tmrow = LDS_TM + (wm * 32 + l15) * 256;
    const int colsw = (l15 & 7) << 4;
#pragma unroll
    for (int rt = 0; rt < 2; ++rt)
#pragma unroll
      for (int jc = 0; jc < 4; ++jc)
        Tall[rt][jc] = *(const f16x8*)(smem + tmrow + rt * 4096 +
                                       ((jc * 64 + g4 * 16) ^ colsw));
  }
  const __half* hbase = (const __half*)(smem + LDS_H) + wm * 32 + l15;

  __half2 hc[2], hn[2];
#pragma unroll
  for (int rt = 0; rt < 2; ++rt) hc[rt] = __half2half2(hbase[rt * 16]);

  // ---- B stream: global->reg, double-buffered ----
  const char* bp = (const char*)w2c + (size_t)(c * 64) * 8192 + wn * 4096 + lane * 16;
  f16x8 Bc[4], Bn[4];
#pragma unroll
  for (int nt = 0; nt < 4; ++nt) Bn[nt] = *(const f16x8*)(bp + nt * 1024);
  bp += 8192;

  f32x4 acc[2][4];
#pragma unroll
  for (int rt = 0; rt < 2; ++rt)
#pragma unroll
    for (int nt = 0; nt < 4; ++nt) acc[rt][nt] = (f32x4){0.f, 0.f, 0.f, 0.f};

  for (int u = 0; u < nu; ++u) {
#pragma unroll
    for (int jc = 0; jc < 4; ++jc) {
#pragma unroll
      for (int nt = 0; nt < 4; ++nt) Bc[nt] = Bn[nt];
      // prefetch next phase's B (tail prefetch past chunk: in-bounds of ws, unused)
#pragma unroll
      for (int nt = 0; nt < 4; ++nt) Bn[nt] = *(const f16x8*)(bp + nt * 1024);
      bp += 8192;
      if (jc == 1) {   // prefetch next u's h (rows < 20 staged; stale at tail, unused)
#pragma unroll
        for (int rt = 0; rt < 2; ++rt)
          hn[rt] = __half2half2(hbase[(u + 1) * 128 + rt * 16]);
      }
      // A-gen from register-resident tm frags
      union uf { f16x8 v; __half2 h[4]; };
      uf a[2];
#pragma unroll
      for (int rt = 0; rt < 2; ++rt) {
        uf t; t.v = Tall[rt][jc];
#pragma unroll
        for (int q = 0; q < 4; ++q) a[rt].h[q] = __hmul2(t.h[q], hc[rt]);
      }
      __builtin_amdgcn_s_setprio(1);
#pragma unroll
      for (int nt = 0; nt < 4; ++nt)
#pragma unroll
        for (int rt = 0; rt < 2; ++rt)
          acc[rt][nt] = __builtin_amdgcn_mfma_f32_16x16x32_f16(a[rt].v, Bc[nt], acc[rt][nt], 0, 0, 0);
      __builtin_amdgcn_s_setprio(0);
    }
#pragma unroll
    for (int rt = 0; rt < 2; ++rt) hc[rt] = hn[rt];
  }

  // epilogue: scatter-add partials (C map: row=(g4*4+r), col=l15 per 16x16 frag)
  const int* dst = EI + NEDGE;
#pragma unroll
  for (int rt = 0; rt < 2; ++rt) {
#pragma unroll
    for (int r = 0; r < 4; ++r) {
      int e = e0 + wm * 32 + rt * 16 + g4 * 4 + r;
      float* row = msg + (size_t)dst[e] * 128 + wn * 64 + l15;
#pragma unroll
      for (int nt = 0; nt < 4; ++nt)
        atomicAdd(row + nt * 16, acc[rt][nt][r]);
    }
  }
}

// ---------------- k3: out = silu(messages) ----------------------------------
__global__ __launch_bounds__(256) void k3_silu(float* __restrict__ out, int n4) {
  int idx = blockIdx.x * 256 + threadIdx.x;
  int stride = gridDim.x * 256;
  f32x4* p = (f32x4*)out;
  for (; idx < n4; idx += stride) {
    f32x4 v = p[idx];
#pragma unroll
    for (int cc = 0; cc < 4; ++cc) v[cc] = fsilu(v[cc]);
    p[idx] = v;
  }
}

extern "C" void kernel_launch(void* const* d_in, const int* in_sizes, int n_in,
                              void* d_out, int out_size, void* d_ws, size_t ws_size,
                              hipStream_t stream) {
  const float* NF = (const float*)d_in[0];
  const int*   EI = (const int*)  d_in[1];
  const float* DI = (const float*)d_in[2];
  const float* W1 = (const float*)d_in[3];
  const float* B1 = (const float*)d_in[4];
  const float* W2 = (const float*)d_in[5];
  const float* B2 = (const float*)d_in[6];
  const float* WT = (const float*)d_in[7];
  float* out = (float*)d_out;

  f16* w2c = (f16*)d_ws;
  f16* ht2 = (f16*)((char*)d_ws + W2C_BYTES);
  f16* tmo = (f16*)((char*)d_ws + W2C_BYTES + HT_BYTES);
  size_t needed = (size_t)W2C_BYTES + HT_BYTES + TM_BYTES;
  if (ws_size < needed) return;  // insufficient scratch: fail loudly

  int nz4 = out_size / 4;
  int zb  = (nz4 + 1023) / 1024;
  k01    <<<dim3(1544 + zb), dim3(256), 0, stream>>>(W2, B2, NF, EI, DI, W1, B1, WT,
                                                     w2c, ht2, tmo, out, nz4);
  k2_gemm<<<dim3(512),       dim3(512), 0, stream>>>(w2c, ht2, tmo, EI, out);
  k3_silu<<<dim3(1024),      dim3(256), 0, stream>>>(out, out_size / 4);
}

// Round 8
// 88.422 us; speedup vs baseline: 2.1698x; 1.0403x over previous
//
#include <hip/hip_runtime.h>
#include <hip/hip_fp16.h>

// ContinuousFilterConv on MI355X (gfx950), round 8.
// filtered[e,i] = sum_{u,j} h[e,u] * tm[e,j] * W2ext[u, i*128+j]
// GEMM C[8192x128] = A[8192x16512] @ B[16512x128], f16 MFMA, A generated on
// the fly (outer product h x tm). K split over 8 u-chunks (c = XCD), grid 512.
// Round 8: round-4 geometry (256 thr, 4 waves of 64e x 64i, VGPR~100, 3
// waves/SIMD) + PREFETCH DISTANCE 2: two static B buffers keyed by jc&1,
// each reloaded with phase p+2's data right after its MFMAs consume it.
// Loads interleaved per-nt after their consuming MFMA group.

typedef _Float16 f16;
typedef __attribute__((ext_vector_type(8))) f16 f16x8;
typedef __attribute__((ext_vector_type(4))) float f32x4;
typedef __attribute__((ext_vector_type(4))) unsigned int u32x4;

#define NEDGE 8192
#define NNODE 20000
#define NG    50
#define KSTEPS 516                       // 129 u-rows * 128 j / 32
#define W2C_BYTES (KSTEPS * 8192)        // [step][nt8][lane64][8] f16
#define HT_BYTES (64 * 132 * 128 * 2)    // [eb][u(132, 128=ones)][el(128)] f16
#define TM_BYTES (NEDGE * 128 * 2)       // [e][j^swz] f16 (mask folded, pre-swizzled)

// k2 LDS map (bytes) — prologue staging only
#define LDS_H   0                        // 20 rows x 256 B = 5120
#define LDS_TM  5120                     // 128 x 256 B (swizzled) = 32768
#define LDS_TOT 37888

static __device__ __forceinline__ float fsilu(float x) { return x / (1.0f + __expf(-x)); }

static __device__ __forceinline__ void gll16(const void* g, void* l) {
  __builtin_amdgcn_global_load_lds(
      (const __attribute__((address_space(1))) unsigned int*)g,
      (__attribute__((address_space(3))) unsigned int*)l, 16, 0, 0);
}

// -------- k01: fused {W2->w2c frag convert | per-edge h,tm | zero out} ------
__global__ __launch_bounds__(256) void k01(const float* __restrict__ W2,
                                           const float* __restrict__ b2,
                                           const float* __restrict__ NF,
                                           const int*   __restrict__ EI,
                                           const float* __restrict__ DI,
                                           const float* __restrict__ W1,
                                           const float* __restrict__ B1,
                                           const float* __restrict__ WT,
                                           f16* __restrict__ w2c,
                                           f16* __restrict__ ht2,
                                           f16* __restrict__ tmo,
                                           float* __restrict__ out, int nz4) {
  __shared__ float df[16][NG];
  __shared__ float s_mask[16];
  __shared__ float s_src[16][128];
  __shared__ float t_tile[16][132];
  __shared__ float h_tile[16][132];
  const int bid = blockIdx.x, tid = threadIdx.x;

  if (bid < 1032) {
    // ---- k0 body: W2 (+b2) -> f16, MFMA-B fragment-linear per K-step ----
    int gidx = bid * 256 + tid;                  // 16B-group id, 516*512 total
    int lane = gidx & 63;
    int nt   = (gidx >> 6) & 7;
    int step = gidx >> 9;
    int k0i = step * 32 + (lane >> 4) * 8;       // first k of this group
    int i   = nt * 16 + (lane & 15);
    int u   = k0i >> 7, j0 = k0i & 127;
    const float* src = (u < 128) ? (W2 + (size_t)u * 16384 + i * 128 + j0)
                                 : (b2 + i * 128 + j0);
    union { f16 s[8]; u32x4 v; } pk;
#pragma unroll
    for (int r = 0; r < 8; ++r) pk.s[r] = (f16)src[r];
    *((u32x4*)w2c + gidx) = pk.v;
    return;
  }
  if (bid < 1544) {
    // ---- k1 body: per-edge h (unmasked) and tm = mask * (src@Wt) ----
    int et = bid - 1032, e0 = et * 16;
    for (int idx = tid; idx < 16 * NG; idx += 256) {
      int e = idx / NG, g = idx - e * NG;
      float d = DI[e0 + e];
      float x = d - (float)g * (30.0f / 49.0f);
      df[e][g] = __expf(-10.0f * x * x);
    }
    if (tid < 16) s_mask[tid] = (DI[e0 + tid] <= 8.0f) ? 1.0f : 0.0f;
    for (int idx = tid; idx < 16 * 128; idx += 256) {
      int e = idx >> 7, u = idx & 127;
      s_src[e][u] = NF[(size_t)EI[e0 + e] * 128 + u];
    }
    __syncthreads();

    int j = tid & 127, es = tid >> 7;
    for (int e = es * 8; e < es * 8 + 8; ++e) {
      float acc = B1[j];
      for (int g = 0; g < NG; ++g) acc += df[e][g] * W1[g * 128 + j];
      h_tile[e][j] = fsilu(acc);
    }
    {
      float acc[8] = {0.f,0.f,0.f,0.f,0.f,0.f,0.f,0.f};
      for (int u = 0; u < 128; ++u) {
        float wv = WT[u * 128 + j];
#pragma unroll
        for (int e8 = 0; e8 < 8; ++e8) acc[e8] += s_src[es * 8 + e8][u] * wv;
      }
#pragma unroll
      for (int e8 = 0; e8 < 8; ++e8) t_tile[es * 8 + e8][j] = acc[e8];
    }
    __syncthreads();

    int eb = et >> 3, el0 = (et & 7) * 16;
    // ht2[eb][u][el]: tid -> (u = tid>>1, half = tid&1)
    {
      int u = tid >> 1, hf = tid & 1;
      union { f16 s[8]; u32x4 v; } pk;
#pragma unroll
      for (int k = 0; k < 8; ++k) pk.s[k] = (f16)h_tile[hf * 8 + k][u];
      *(u32x4*)(ht2 + ((size_t)eb * 132 + u) * 128 + el0 + hf * 8) = pk.v;
    }
    if (tid < 16) ht2[((size_t)eb * 132 + 128) * 128 + el0 + tid] = (f16)1.0f; // ones (b2)
    // tm[e][j], mask folded, PRE-SWIZZLED column
    {
      int e = tid >> 4, cc = tid & 15;
      float m = s_mask[e];
      union { f16 s[8]; u32x4 v; } pk;
#pragma unroll
      for (int k = 0; k < 8; ++k) pk.s[k] = (f16)(m * t_tile[e][cc * 8 + k]);
      int col = (cc * 16) ^ ((e & 7) << 4);
      *(u32x4*)((char*)tmo + (size_t)(e0 + e) * 256 + col) = pk.v;
    }
    return;
  }
  // ---- zero d_out ----
  {
    int base = (bid - 1544) * 1024;
    f32x4 z = {0.f, 0.f, 0.f, 0.f};
#pragma unroll
    for (int k = 0; k < 4; ++k) {
      int i4 = base + k * 256 + tid;
      if (i4 < nz4) ((f32x4*)out)[i4] = z;
    }
  }
}

// ---------------- k2: fused outer-product GEMM + scatter-add ----------------
// grid 512: chunk c = bid&7 (16 u, c==7: 17 incl. b2 row), eb = bid>>3.
// Block: 4 waves 2x2 over 128e x 128i; wave = 64e x 64i; acc[4][4] f32x4.
// Main loop: no barriers, no LDS. tm frags in VGPRs; B global->reg,
// 2 static buffers (parity jc&1), prefetch distance 2.
__global__ __launch_bounds__(256, 2) void k2_gemm(const f16* __restrict__ w2c,
                                                  const f16* __restrict__ ht2,
                                                  const f16* __restrict__ tm,
                                                  const int* __restrict__ EI,
                                                  float* __restrict__ msg) {
  __shared__ u32x4 smem_v[LDS_TOT / 16];
  char* smem = (char*)smem_v;

  const int bid = blockIdx.x;
  const int c   = bid & 7;
  const int eb  = bid >> 3;
  const int e0  = eb * 128;
  const int nu  = (c == 7) ? 17 : 16;
  const int tid = threadIdx.x, w = tid >> 6, lane = tid & 63;
  const int l15 = lane & 15, g4 = lane >> 4;
  const int wm = w >> 1, wn = w & 1;

  // ---- prologue staging (tm swizzled + h), one-time ----
  {
    const char* tsrc = (const char*)tm + (size_t)e0 * 256 + w * 8192;
#pragma unroll
    for (int q = 0; q < 8; ++q)
      gll16(tsrc + q * 1024 + lane * 16,
            smem + LDS_TM + w * 8192 + q * 1024 + lane * 16);
  }
  if (w == 0) {   // 20 h rows
    const char* hsrc = (const char*)ht2 + ((size_t)eb * 132 + c * 16) * 256;
#pragma unroll
    for (int q = 0; q < 5; ++q)
      gll16(hsrc + q * 1024 + lane * 16, smem + LDS_H + q * 1024 + lane * 16);
  }
  __syncthreads();

  // ---- tm A-frags: u-invariant -> load ALL into registers once ----
  f16x8 Tall[4][4];
  {
    const int tmrow = LDS_TM + (wm * 64 + l15) * 256;
    const int colsw = (l15 & 7) << 4;
#pragma unroll
    for (int rt = 0; rt < 4; ++rt)
#pragma unroll
      for (int jc = 0; jc < 4; ++jc)
        Tall[rt][jc] = *(const f16x8*)(smem + tmrow + rt * 4096 +
                                       ((jc * 64 + g4 * 16) ^ colsw));
  }
  const __half* hbase = (const __half*)(smem + LDS_H) + wm * 64 + l15;

  __half2 hc[4], hn[4];
#pragma unroll
  for (int rt = 0; rt < 4; ++rt) hc[rt] = __half2half2(hbase[rt * 16]);

  // ---- B stream: global->reg, 2 static buffers, distance-2 prefetch ----
  const char* bp = (const char*)w2c + (size_t)(c * 64) * 8192 + wn * 4096 + lane * 16;
  const size_t offmax = (size_t)(nu * 4 - 1) * 8192;   // clamp for tail prefetch
  f16x8 B0[4], B1[4];
#pragma unroll
  for (int nt = 0; nt < 4; ++nt) B0[nt] = *(const f16x8*)(bp + nt * 1024);          // ph 0
#pragma unroll
  for (int nt = 0; nt < 4; ++nt) B1[nt] = *(const f16x8*)(bp + 8192 + nt * 1024);   // ph 1
  size_t off = 2 * 8192;                                // next prefetch target: ph 2

  f32x4 acc[4][4];
#pragma unroll
  for (int rt = 0; rt < 4; ++rt)
#pragma unroll
    for (int nt = 0; nt < 4; ++nt) acc[rt][nt] = (f32x4){0.f, 0.f, 0.f, 0.f};

  for (int u = 0; u < nu; ++u) {
#pragma unroll
    for (int jc = 0; jc < 4; ++jc) {
      if (jc == 1) {   // prefetch next u's h (rows < 20 staged; tail value unused)
#pragma unroll
        for (int rt = 0; rt < 4; ++rt)
          hn[rt] = __half2half2(hbase[(u + 1) * 128 + rt * 16]);
      }
      // A-gen from register-resident tm frags
      union uf { f16x8 v; __half2 h[4]; };
      uf a[4];
#pragma unroll
      for (int rt = 0; rt < 4; ++rt) {
        uf t; t.v = Tall[rt][jc];
#pragma unroll
        for (int q = 0; q < 4; ++q) a[rt].h[q] = __hmul2(t.h[q], hc[rt]);
      }
      // per-nt: 4 MFMAs consume B[jc&1][nt], then reload it with phase p+2
      size_t o = off; if (o > offmax) o = offmax;
      __builtin_amdgcn_s_setprio(1);
#pragma unroll
      for (int nt = 0; nt < 4; ++nt) {
        if ((jc & 1) == 0) {
#pragma unroll
          for (int rt = 0; rt < 4; ++rt)
            acc[rt][nt] = __builtin_amdgcn_mfma_f32_16x16x32_f16(a[rt].v, B0[nt], acc[rt][nt], 0, 0, 0);
          B0[nt] = *(const f16x8*)(bp + o + nt * 1024);
        } else {
#pragma unroll
          for (int rt = 0; rt < 4; ++rt)
            acc[rt][nt] = __builtin_amdgcn_mfma_f32_16x16x32_f16(a[rt].v, B1[nt], acc[rt][nt], 0, 0, 0);
          B1[nt] = *(const f16x8*)(bp + o + nt * 1024);
        }
      }
      __builtin_amdgcn_s_setprio(0);
      off += 8192;
    }
#pragma unroll
    for (int rt = 0; rt < 4; ++rt) hc[rt] = hn[rt];
  }

  // epilogue: scatter-add partials (C map: row=(g4*4+r), col=l15 per 16x16 frag)
  const int* dst = EI + NEDGE;
#pragma unroll
  for (int rt = 0; rt < 4; ++rt) {
#pragma unroll
    for (int r = 0; r < 4; ++r) {
      int e = e0 + wm * 64 + rt * 16 + g4 * 4 + r;
      float* row = msg + (size_t)dst[e] * 128 + wn * 64 + l15;
#pragma unroll
      for (int nt = 0; nt < 4; ++nt)
        atomicAdd(row + nt * 16, acc[rt][nt][r]);
    }
  }
}

// ---------------- k3: out = silu(messages) ----------------------------------
__global__ __launch_bounds__(256) void k3_silu(float* __restrict__ out, int n4) {
  int idx = blockIdx.x * 256 + threadIdx.x;
  int stride = gridDim.x * 256;
  f32x4* p = (f32x4*)out;
  for (; idx < n4; idx += stride) {
    f32x4 v = p[idx];
#pragma unroll
    for (int cc = 0; cc < 4; ++cc) v[cc] = fsilu(v[cc]);
    p[idx] = v;
  }
}

extern "C" void kernel_launch(void* const* d_in, const int* in_sizes, int n_in,
                              void* d_out, int out_size, void* d_ws, size_t ws_size,
                              hipStream_t stream) {
  const float* NF = (const float*)d_in[0];
  const int*   EI = (const int*)  d_in[1];
  const float* DI = (const float*)d_in[2];
  const float* W1 = (const float*)d_in[3];
  const float* B1 = (const float*)d_in[4];
  const float* W2 = (const float*)d_in[5];
  const float* B2 = (const float*)d_in[6];
  const float* WT = (const float*)d_in[7];
  float* out = (float*)d_out;

  f16* w2c = (f16*)d_ws;
  f16* ht2 = (f16*)((char*)d_ws + W2C_BYTES);
  f16* tmo = (f16*)((char*)d_ws + W2C_BYTES + HT_BYTES);
  size_t needed = (size_t)W2C_BYTES + HT_BYTES + TM_BYTES;
  if (ws_size < needed) return;  // insufficient scratch: fail loudly

  int nz4 = out_size / 4;
  int zb  = (nz4 + 1023) / 1024;
  k01    <<<dim3(1544 + zb), dim3(256), 0, stream>>>(W2, B2, NF, EI, DI, W1, B1, WT,
                                                     w2c, ht2, tmo, out, nz4);
  k2_gemm<<<dim3(512),       dim3(256), 0, stream>>>(w2c, ht2, tmo, EI, out);
  k3_silu<<<dim3(1024),      dim3(256), 0, stream>>>(out, out_size / 4);
}